// Round 5
// baseline (440.319 us; speedup 1.0000x reference)
//
#include <hip/hip_runtime.h>

// ---------------- problem constants ----------------
constexpr int N_NODES  = 50000;
constexpr int N_EDGES  = 800000;
constexpr int N_GRAPHS = 512;
constexpr int F_IN     = 128;
constexpr int HID      = 256;
constexpr int NPAD     = 50048;   // 782*64

typedef short short8 __attribute__((ext_vector_type(8)));
typedef float f32x4  __attribute__((ext_vector_type(4)));

// bf16 helpers (raw ushort storage; RNE rounding)
__device__ __forceinline__ unsigned short f2b(float f) {
    unsigned u = __float_as_uint(f);
    u += 0x7fffu + ((u >> 16) & 1u);
    return (unsigned short)(u >> 16);
}
__device__ __forceinline__ float b2f_lo(unsigned u) { return __uint_as_float(u << 16); }
__device__ __forceinline__ float b2f_hi(unsigned u) { return __uint_as_float(u & 0xffff0000u); }

// ---------------- fused prep: deg histogram + x->bf16 + weights -> B-fragment layout ----------------
// Wfrag ushort index: half*(K*128) + ((k>>3)*128 + (n&127))*8 + (k&7), half = n>>7
__global__ __launch_bounds__(256) void prep_kernel(
    const int* __restrict__ dst, int* __restrict__ deg,
    const float* __restrict__ x, unsigned short* __restrict__ x_bf,
    const float* __restrict__ W0, const float* __restrict__ W1, const float* __restrict__ W2,
    unsigned short* __restrict__ Wt0, unsigned short* __restrict__ Wt1, unsigned short* __restrict__ Wt2)
{
    const int b = blockIdx.x, t = threadIdx.x;
    if (b < 3125) {
        int e = b * 256 + t;                       // 3125*256 == 800000
        atomicAdd(&deg[dst[e]], 1);
    } else if (b < 9375) {
        int i = (b - 3125) * 256 + t;              // 6250*256 == 1.6M float4
        float4 v = *reinterpret_cast<const float4*>(x + (size_t)i * 4);
        unsigned r0 = (unsigned)f2b(v.x) | ((unsigned)f2b(v.y) << 16);
        unsigned r1 = (unsigned)f2b(v.z) | ((unsigned)f2b(v.w) << 16);
        *reinterpret_cast<uint2*>(x_bf + (size_t)i * 4) = make_uint2(r0, r1);
    } else {
        int i = (b - 9375) * 256 + t;              // 640*256 == 163840
        const float* W; unsigned short* Wt; int K; int j;
        if (i < 32768)      { W = W0; Wt = Wt0; K = 128; j = i; }
        else if (i < 98304) { W = W1; Wt = Wt1; K = 256; j = i - 32768; }
        else                { W = W2; Wt = Wt2; K = 256; j = i - 98304; }
        int k = j >> 8, n = j & 255;
        int idx = (n >> 7) * (K * 128) + (((k >> 3) * 128 + (n & 127)) << 3) + (k & 7);
        Wt[idx] = f2b(W[j]);
    }
}

// ---------------- parallel scan (3 kernels) + dis fused ----------------
__global__ void block_sum_dis_kernel(const int* __restrict__ deg, int* __restrict__ bsum,
                                     float* __restrict__ dis, int n) {
    __shared__ int sm[256];
    int t = threadIdx.x, base = blockIdx.x * 1024;
    int s = 0;
    #pragma unroll
    for (int i = 0; i < 4; ++i) {
        int idx = base + t + i * 256;
        if (idx < n) { int d = deg[idx]; s += d; dis[idx] = rsqrtf((float)d + 1.0f); }
    }
    sm[t] = s; __syncthreads();
    for (int o = 128; o > 0; o >>= 1) { if (t < o) sm[t] += sm[t + o]; __syncthreads(); }
    if (t == 0) bsum[blockIdx.x] = sm[0];
}

__global__ void scan_bsum_kernel(int* __restrict__ bsum, int nb) {   // 1 block, 64 threads
    __shared__ int sm[64];
    int t = threadIdx.x;
    int v = (t < nb) ? bsum[t] : 0;
    sm[t] = v; __syncthreads();
    for (int o = 1; o < 64; o <<= 1) {
        int a = (t >= o) ? sm[t - o] : 0; __syncthreads();
        sm[t] += a; __syncthreads();
    }
    if (t < nb) bsum[t] = sm[t] - v;   // exclusive
}

__global__ void scan_local_kernel(const int* __restrict__ deg, const int* __restrict__ bsum,
                                  int* __restrict__ row_start, int* __restrict__ cursor, int n) {
    __shared__ int sm[256];
    int t = threadIdx.x, base = blockIdx.x * 1024;
    int idx0 = base + t * 4;
    int v[4], s = 0;
    #pragma unroll
    for (int i = 0; i < 4; ++i) { int id = idx0 + i; v[i] = (id < n) ? deg[id] : 0; s += v[i]; }
    sm[t] = s; __syncthreads();
    for (int o = 1; o < 256; o <<= 1) {
        int a = (t >= o) ? sm[t - o] : 0; __syncthreads();
        sm[t] += a; __syncthreads();
    }
    int excl = bsum[blockIdx.x] + sm[t] - s;
    #pragma unroll
    for (int i = 0; i < 4; ++i) {
        int id = idx0 + i;
        if (id < n) { row_start[id] = excl; cursor[id] = excl; }
        excl += v[i];
    }
    if (blockIdx.x == gridDim.x - 1 && t == 255) row_start[n] = excl;  // == N_EDGES
}

// ---------------- CSR scatter: entry = (src, w_bits) ----------------
__global__ void fill_csr(const int* __restrict__ src, const int* __restrict__ dst,
                         const float* __restrict__ dis, int* __restrict__ cursor,
                         int2* __restrict__ csr) {
    int e = blockIdx.x * blockDim.x + threadIdx.x;
    if (e >= N_EDGES) return;
    int s = src[e], d = dst[e];
    int pos = atomicAdd(&cursor[d], 1);
    float w = dis[s] * dis[d];
    csr[pos] = make_int2(s, __float_as_int(w));
}

// ---------------- fused layer: agg (gather into LDS, fragment layout) + MFMA GEMM ----------------
// Block = 64-node panel, 256 threads = 4 waves.
// Gather: wave w owns nodes [panel*64 + w*16, +16); per node, NSUB subgroups of LPR lanes
// each pull one edge (16B/lane dwordx4), fp32 accumulate, shfl-combine, bf16-pack into
// XOR-swizzled LDS A-panel: chunk(row, kc) = row*CPR + (kc ^ (row&7)).
// GEMM: 4 waves, wave w = 64-col strip; A frags from LDS, W frags direct from global (L2-hot).
template<int K>
__global__ __launch_bounds__(256, 4) void layer_fused(
    const unsigned short* __restrict__ hin,     // row-major [*, K] bf16
    const int* __restrict__ row_start, const int2* __restrict__ csr,
    const float* __restrict__ dis,
    const unsigned short* __restrict__ Wfrag,   // [2][K/8][128][8]
    const float* __restrict__ bias,
    unsigned short* __restrict__ hout)          // row-major [NPAD, 256] bf16
{
    constexpr int CPR  = K / 8;     // 16B chunks per row: 32 (K=256) / 16 (K=128)
    constexpr int LPR  = K / 8;     // lanes per row-gather
    constexpr int NSUB = 64 / LPR;  // edge subgroups per wave
    __shared__ __align__(16) uint4 Alds[64 * CPR];   // 32KB (K=256) / 16KB (K=128)

    const int t    = threadIdx.x;
    const int lane = t & 63;
    const int w    = t >> 6;
    const int panel = blockIdx.x;
    const int sub  = lane / LPR;
    const int fc   = lane % LPR;

    // ---------------- gather phase ----------------
    for (int nn = 0; nn < 16; ++nn) {
        const int r    = w * 16 + nn;          // LDS row 0..63
        const int node = panel * 64 + r;
        float acc[8];
        if (node < N_NODES) {
            {   // self-loop term (sub 0 only contributes)
                float dn = dis[node];
                float sw = (sub == 0) ? dn * dn : 0.0f;
                uint2 u2[2];
                *reinterpret_cast<uint4*>(u2) =
                    *reinterpret_cast<const uint4*>(hin + (size_t)node * K + fc * 8);
                #pragma unroll
                for (int h = 0; h < 2; ++h) {
                    acc[h * 4 + 0] = b2f_lo(u2[h].x) * sw;
                    acc[h * 4 + 1] = b2f_hi(u2[h].x) * sw;
                    acc[h * 4 + 2] = b2f_lo(u2[h].y) * sw;
                    acc[h * 4 + 3] = b2f_hi(u2[h].y) * sw;
                }
            }
            int j = row_start[node] + sub;
            const int end = row_start[node + 1];
            for (; j + 3 * NSUB < end; j += 4 * NSUB) {
                int2 c[4];
                #pragma unroll
                for (int u = 0; u < 4; ++u) c[u] = csr[j + u * NSUB];
                #pragma unroll
                for (int u = 0; u < 4; ++u) {
                    float wgt = __int_as_float(c[u].y);
                    uint2 g[2];
                    *reinterpret_cast<uint4*>(g) =
                        *reinterpret_cast<const uint4*>(hin + (size_t)c[u].x * K + fc * 8);
                    #pragma unroll
                    for (int h = 0; h < 2; ++h) {
                        acc[h * 4 + 0] = fmaf(b2f_lo(g[h].x), wgt, acc[h * 4 + 0]);
                        acc[h * 4 + 1] = fmaf(b2f_hi(g[h].x), wgt, acc[h * 4 + 1]);
                        acc[h * 4 + 2] = fmaf(b2f_lo(g[h].y), wgt, acc[h * 4 + 2]);
                        acc[h * 4 + 3] = fmaf(b2f_hi(g[h].y), wgt, acc[h * 4 + 3]);
                    }
                }
            }
            for (; j < end; j += NSUB) {
                int2 c0 = csr[j];
                float wgt = __int_as_float(c0.y);
                uint2 g[2];
                *reinterpret_cast<uint4*>(g) =
                    *reinterpret_cast<const uint4*>(hin + (size_t)c0.x * K + fc * 8);
                #pragma unroll
                for (int h = 0; h < 2; ++h) {
                    acc[h * 4 + 0] = fmaf(b2f_lo(g[h].x), wgt, acc[h * 4 + 0]);
                    acc[h * 4 + 1] = fmaf(b2f_hi(g[h].x), wgt, acc[h * 4 + 1]);
                    acc[h * 4 + 2] = fmaf(b2f_lo(g[h].y), wgt, acc[h * 4 + 2]);
                    acc[h * 4 + 3] = fmaf(b2f_hi(g[h].y), wgt, acc[h * 4 + 3]);
                }
            }
            // combine subgroup partials
            #pragma unroll
            for (int k = 0; k < 8; ++k) {
                #pragma unroll
                for (int off = LPR; off < 64; off <<= 1)
                    acc[k] += __shfl_xor(acc[k], off, 64);
            }
        } else {
            #pragma unroll
            for (int k = 0; k < 8; ++k) acc[k] = 0.0f;
        }

        if (sub == 0) {
            uint2 rv[2];
            #pragma unroll
            for (int h = 0; h < 2; ++h) {
                rv[h].x = (unsigned)f2b(acc[h * 4 + 0]) | ((unsigned)f2b(acc[h * 4 + 1]) << 16);
                rv[h].y = (unsigned)f2b(acc[h * 4 + 2]) | ((unsigned)f2b(acc[h * 4 + 3]) << 16);
            }
            Alds[r * CPR + (fc ^ (r & 7))] = *reinterpret_cast<uint4*>(rv);
        }
    }
    __syncthreads();

    // ---------------- GEMM phase ----------------
    const int q = lane >> 4, m = lane & 15;
    f32x4 acc4[4][4] = {};
    const unsigned short* bptr = Wfrag + (size_t)(w >> 1) * (K * 128);
    const int colh = (w & 1) * 64;   // column base within the 128-col half

    #pragma unroll
    for (int kb = 0; kb < K / 32; ++kb) {
        const int kc = kb * 4 + q;
        short8 af[4], bf[4];
        #pragma unroll
        for (int i = 0; i < 4; ++i) {
            uint4 v = Alds[(i * 16 + m) * CPR + (kc ^ (m & 7))];
            af[i] = *reinterpret_cast<short8*>(&v);
        }
        #pragma unroll
        for (int jn = 0; jn < 4; ++jn)
            bf[jn] = *reinterpret_cast<const short8*>(&bptr[(size_t)(kc * 128 + colh + jn * 16 + m) * 8]);
        #pragma unroll
        for (int i = 0; i < 4; ++i)
            #pragma unroll
            for (int jn = 0; jn < 4; ++jn)
                acc4[i][jn] = __builtin_amdgcn_mfma_f32_16x16x32_bf16(af[i], bf[jn], acc4[i][jn], 0, 0, 0);
    }

    // epilogue: C/D layout col = lane&15, row = (lane>>4)*4 + reg; row-major bf16 out
    #pragma unroll
    for (int jn = 0; jn < 4; ++jn) {
        const int col = w * 64 + jn * 16 + m;
        const float bj = bias[col];
        #pragma unroll
        for (int i = 0; i < 4; ++i) {
            const int rowb = panel * 64 + i * 16 + q * 4;
            #pragma unroll
            for (int r2 = 0; r2 < 4; ++r2) {
                float v = acc4[i][jn][r2] + bj;
                v = fmaxf(v, 0.f);
                hout[(size_t)(rowb + r2) * 256 + col] = f2b(v);
            }
        }
    }
}

// ---------------- fused pool + MLP head ----------------
__global__ __launch_bounds__(256) void pool_mlp_kernel(
    const unsigned short* __restrict__ h, const int* __restrict__ batch,
    const float* __restrict__ Wm1, const float* __restrict__ bm1,
    const float* __restrict__ Wm2, const float* __restrict__ bm2,
    float* __restrict__ out)
{
    __shared__ float p[HID];
    __shared__ float red[HID];
    __shared__ int se[2];
    const int g = blockIdx.x, t = threadIdx.x;
    if (t < 2) {
        int target = g + t;
        int lo = 0, hi = N_NODES;
        while (lo < hi) { int mid = (lo + hi) >> 1; if (batch[mid] < target) lo = mid + 1; else hi = mid; }
        se[t] = lo;
    }
    __syncthreads();
    const int s = se[0], e = se[1];
    float acc = 0.f;
    for (int n = s; n < e; ++n) acc += b2f_lo((unsigned)h[(size_t)n * HID + t]);
    p[t] = acc / fmaxf((float)(e - s), 1.0f);
    __syncthreads();
    float a2 = bm1[t];
    for (int k = 0; k < HID; ++k) a2 = fmaf(p[k], Wm1[k * HID + t], a2);
    red[t] = fmaxf(a2, 0.f) * Wm2[t];
    __syncthreads();
    for (int o = 128; o > 0; o >>= 1) {
        if (t < o) red[t] += red[t + o];
        __syncthreads();
    }
    if (t == 0) out[g] = red[0] + bm2[0];
}

// ---------------- launch ----------------
extern "C" void kernel_launch(void* const* d_in, const int* in_sizes, int n_in,
                              void* d_out, int out_size, void* d_ws, size_t ws_size,
                              hipStream_t stream) {
    const float* x    = (const float*)d_in[0];
    const int*   ei   = (const int*)d_in[1];
    const int*   batch= (const int*)d_in[2];
    const float* W0   = (const float*)d_in[3];
    const float* b0   = (const float*)d_in[4];
    const float* W1   = (const float*)d_in[5];
    const float* b1   = (const float*)d_in[6];
    const float* W2   = (const float*)d_in[7];
    const float* b2   = (const float*)d_in[8];
    const float* Wm1  = (const float*)d_in[9];
    const float* bm1  = (const float*)d_in[10];
    const float* Wm2  = (const float*)d_in[11];
    const float* bm2  = (const float*)d_in[12];
    float* out = (float*)d_out;

    char* ws = (char*)d_ws;
    size_t off = 0;
    auto alloc = [&](size_t bytes) -> void* {
        void* p = ws + off;
        off += (bytes + 255) & ~(size_t)255;
        return p;
    };
    int*   deg       = (int*)  alloc((size_t)N_NODES * 4);
    float* dis       = (float*)alloc((size_t)N_NODES * 4);
    int*   row_start = (int*)  alloc((size_t)(N_NODES + 1) * 4);
    int*   cursor    = (int*)  alloc((size_t)N_NODES * 4);
    int*   bsum      = (int*)  alloc((size_t)64 * 4);
    int2*  csr       = (int2*) alloc((size_t)N_EDGES * 8);
    unsigned short* x_bf = (unsigned short*)alloc((size_t)N_NODES * F_IN * 2);
    unsigned short* Wt0  = (unsigned short*)alloc((size_t)F_IN * HID * 2);
    unsigned short* Wt1  = (unsigned short*)alloc((size_t)HID * HID * 2);
    unsigned short* Wt2  = (unsigned short*)alloc((size_t)HID * HID * 2);
    unsigned short* h1   = (unsigned short*)alloc((size_t)NPAD * HID * 2);
    unsigned short* h2   = (unsigned short*)alloc((size_t)NPAD * HID * 2);

    const int* src = ei;
    const int* dst = ei + N_EDGES;
    const int NB = (N_NODES + 1023) / 1024;   // 49

    hipMemsetAsync(deg, 0, (size_t)N_NODES * 4, stream);
    prep_kernel         <<<10015, 256, 0, stream>>>(dst, deg, x, x_bf, W0, W1, W2, Wt0, Wt1, Wt2);
    block_sum_dis_kernel<<<NB, 256, 0, stream>>>(deg, bsum, dis, N_NODES);
    scan_bsum_kernel    <<<1, 64, 0, stream>>>(bsum, NB);
    scan_local_kernel   <<<NB, 256, 0, stream>>>(deg, bsum, row_start, cursor, N_NODES);
    fill_csr            <<<(N_EDGES + 255) / 256, 256, 0, stream>>>(src, dst, dis, cursor, csr);

    // three fused GCN layers (agg + GEMM + bias + ReLU each)
    layer_fused<F_IN><<<NPAD / 64, 256, 0, stream>>>(x_bf, row_start, csr, dis, Wt0, b0, h1);
    layer_fused<HID> <<<NPAD / 64, 256, 0, stream>>>(h1,   row_start, csr, dis, Wt1, b1, h2);
    layer_fused<HID> <<<NPAD / 64, 256, 0, stream>>>(h2,   row_start, csr, dis, Wt2, b2, h1);

    pool_mlp_kernel<<<N_GRAPHS, HID, 0, stream>>>(h1, batch, Wm1, bm1, Wm2, bm2, out);
}